// Round 14
// baseline (3871.835 us; speedup 1.0000x reference)
//
#include <hip/hip_runtime.h>

#define THREADS 512
#define T_TOT 432
#define T_IN  144
#define T_OUT 288

// LDS float4-granule offsets (R13 layout, unchanged)
#define WS4     1552            // per-mat W stride (f4)
#define HA_OFF  4656            // 3*1552
#define HB_OFF  6704            // HA_OFF + 2048
#define PRJ_OFFf 35008          // (HB_OFF+2048)*4 (float index)
#define LDS_BYTES 141056        // (PRJ_OFFf+256)*4

// ws layout (floats): h1b0 [0,64K) h1b1 [64K,128K) h2b0 [128K,192K) h2b1 [192K,256K)
//   (global h layout: [k=256][b=256]) — exchanged via sc0/sc1 (MALL-coherent) ops only
// counters: 512 uints at ws+262144; group bt: cntA = +bt*64, cntB = +bt*64+32 (relaxed RMW only)
// R14 = R13 (passing, 3.79ms) + 512-thread blocks (2 waves/SIMD). K-work split by
// lane bit jh=b5; fold via permlane32_swap (lane^32) AFTER extraction (3 floats).
// R10-12's toxic reorders (x-hoist, SLOADC-before-REDEX) are NOT present.

typedef float v2f __attribute__((ext_vector_type(2)));
typedef int   i2v __attribute__((ext_vector_type(2)));
union f4u { float4 f; v2f h[2]; };

#define PKFMA_LO(acc, hh, w2) asm("v_pk_fma_f32 %0, %1, %2, %0 op_sel:[0,0,0] op_sel_hi:[1,0,1]" \
                                  : "+v"(acc) : "v"(hh), "v"(w2))
#define PKFMA_HI(acc, hh, w2) asm("v_pk_fma_f32 %0, %1, %2, %0 op_sel:[0,1,0] op_sel_hi:[1,1,1]" \
                                  : "+v"(acc) : "v"(hh), "v"(w2))

#define VMWAIT0() do { asm volatile("s_waitcnt vmcnt(0)" ::: "memory"); \
                       __builtin_amdgcn_sched_barrier(0); } while(0)

__device__ __forceinline__ float sigf(float x){ return 1.0f/(1.0f + __expf(-x)); }
__device__ __forceinline__ float tanhfast(float x){ return 1.0f - 2.0f/(__expf(2.0f*x)+1.0f); }

template<int CTRL>
__device__ __forceinline__ float4 dpp_add(float4 v){
  float4 r;
  r.x = v.x + __int_as_float(__builtin_amdgcn_update_dpp(0, __float_as_int(v.x), CTRL, 0xf, 0xf, true));
  r.y = v.y + __int_as_float(__builtin_amdgcn_update_dpp(0, __float_as_int(v.y), CTRL, 0xf, 0xf, true));
  r.z = v.z + __int_as_float(__builtin_amdgcn_update_dpp(0, __float_as_int(v.z), CTRL, 0xf, 0xf, true));
  r.w = v.w + __int_as_float(__builtin_amdgcn_update_dpp(0, __float_as_int(v.w), CTRL, 0xf, 0xf, true));
  return r;
}
// 16-lane K-reduction (proven R9/R13)
__device__ __forceinline__ float4 kred16(float4 v){
  v = dpp_add<177>(v);     // quad_perm [1,0,3,2]
  v = dpp_add<78>(v);      // quad_perm [2,3,0,1]
  v = dpp_add<0x141>(v);   // ROW_HALF_MIRROR
  v = dpp_add<0x140>(v);   // ROW_MIRROR
  return v;
}
// fold lane l with lane l^32 (the jh pair). Sum commutes -> bit-identical on both.
__device__ __forceinline__ float fold32(float v){
  i2v r = __builtin_amdgcn_permlane32_swap(__float_as_int(v), __float_as_int(v), false, false);
  return __int_as_float(r.x) + __int_as_float(r.y);
}

extern "C" __global__ void gru_init(float* __restrict__ ws, float* __restrict__ out,
                                    const float* __restrict__ b_proj){
  int i = blockIdx.x*256 + threadIdx.x;
  if (i < 262144) ws[i] = 0.0f;
  if (i < 512) ((unsigned*)(ws + 262144))[i] = 0u;
  if (i < 73728) out[i] = b_proj[0];
}

typedef float v4f __attribute__((ext_vector_type(4)));

extern "C" __global__ void __launch_bounds__(THREADS, 2) gru_persist(
    const float* __restrict__ x,
    const float* __restrict__ wih0, const float* __restrict__ whh0,
    const float* __restrict__ bih0, const float* __restrict__ bhh0,
    const float* __restrict__ wih1, const float* __restrict__ whh1,
    const float* __restrict__ bih1, const float* __restrict__ bhh1,
    const float* __restrict__ wproj,
    float* __restrict__ out, float* __restrict__ ws)
{
  extern __shared__ float lds[];
  float4* WL4 = (float4*)lds;
  float4* HA4 = WL4 + HA_OFF;
  float4* HB4 = WL4 + HB_OFF;
  const float* HAf = (const float*)HA4;
  const float* HBf = (const float*)HB4;
  float* PRJ = lds + PRJ_OFFf;

  const int tid = threadIdx.x;          // 0..511
  const int bt  = blockIdx.x & 7;       // batch tile (XCD-local group)
  const int g   = blockIdx.x >> 3;      // hidden slice (8 rows)
  const int kg  = tid & 15;             // 16-way in-lane K split (bits 0-3)
  const int jh  = (tid >> 5) & 1;       // K half (bit 5 = lane^32 partner)
  const int wv  = tid >> 6;             // 0..7
  const int rh  = wv >> 2;              // row half
  const int cq  = ((wv & 3) << 1) | ((tid >> 4) & 1);   // col quad 0..7
  // owner cell (lane-local extraction; duplicated across jh, folded by fold32)
  const int hrow = (rh << 2) | (kg >> 2);
  const int col  = (cq << 2) | (kg & 3);
  const int rowg = g*8 + hrow;
  const int btb  = bt << 5;

  float* h1b0 = ws;
  float* h1b1 = ws + 65536;
  float* h2b0 = ws + 131072;
  float* h2b1 = ws + 196608;
  unsigned* cntA = ((unsigned*)(ws + 262144)) + (bt << 6);
  unsigned* cntB = cntA + 32;

  // ---- one-time: W slices -> LDS [k4*24 + row + (k4>>2)] ----
  {
    const float* srcs[3] = {whh0, wih1, whh1};
    #pragma unroll
    for (int m = 0; m < 3; m++){
      const float* S = srcs[m];
      for (int i = 0; i < 3; i++){
        int idx = tid + (i << 9);          // 0..1535
        int row = idx % 24;
        int k4  = idx / 24;
        int gate = row >> 3, hh = row & 7;
        float4 v = *(const float4*)(S + (gate*256 + g*8 + hh)*256 + (k4 << 2));
        WL4[m*WS4 + k4*24 + row + (k4 >> 2)] = v;
      }
    }
  }
  float wi0[3][10];
  float bi0g[3], bh0g[3], bi1g[3], bh1g[3];
  #pragma unroll
  for (int G = 0; G < 3; G++){
    #pragma unroll
    for (int d = 0; d < 10; d++) wi0[G][d] = wih0[(G*256 + rowg)*10 + d];
    bi0g[G] = bih0[G*256 + rowg];
    bh0g[G] = bhh0[G*256 + rowg];
    bi1g[G] = bih1[G*256 + rowg];
    bh1g[G] = bhh1[G*256 + rowg];
  }
  const float wp = wproj[rowg];
  const int hIdx = (rowg << 5) + ((((col >> 2) + (rowg >> 4)) & 7) << 2) + (col & 3);

  v4f hreg[4];
  auto SLOADC = [&](const float* __restrict__ hg){
    #pragma unroll
    for (int i = 0; i < 4; i++){
      int idx = tid + (i << 9);            // 0..2047
      const float* p = hg + ((idx >> 3) << 8) + btb + ((idx & 7) << 2);
      asm volatile("global_load_dwordx4 %0, %1, off sc0 sc1"
                   : "=v"(hreg[i]) : "v"(p) : "memory");
    }
  };
  auto SWRITE = [&](float4* __restrict__ H4){
    #pragma unroll
    for (int i = 0; i < 4; i++){
      int idx = tid + (i << 9);
      int k = idx >> 3, q = idx & 7;
      *(v4f*)&H4[(k << 3) + ((q + (k >> 4)) & 7)] = hreg[i];
    }
  };
  auto HSTORE = [&](float* p, float v){
    asm volatile("global_store_dword %0, %1, off sc0 sc1" :: "v"(p), "v"(v) : "memory");
  };

  // ---- GEMM: 12 rows x 1 quad x 8 k per thread; packed v_pk_fma_f32 ----
  auto GEMM3 = [&](const float4* __restrict__ H4, int m, f4u (&acc)[3][4]){
    const int wb = m*WS4;
    #pragma unroll
    for (int j = 0; j < 2; j++){
      const int k4 = (kg << 2) + (jh << 1) + j;
      const int wr = wb + k4*24 + kg;          // skew k4>>2 == kg
      f4u wf[3][4];
      #pragma unroll
      for (int gte = 0; gte < 3; gte++)
        #pragma unroll
        for (int ri = 0; ri < 4; ri++)
          wf[gte][ri].f = WL4[wr + (gte << 3) + (rh << 2) + ri];
      #pragma unroll
      for (int dk = 0; dk < 4; dk++){
        const int kidx = (k4 << 2) + dk;       // kidx>>4 == kg
        f4u hv; hv.f = H4[(kidx << 3) + ((cq + kg) & 7)];
        #pragma unroll
        for (int gte = 0; gte < 3; gte++)
          #pragma unroll
          for (int ri = 0; ri < 4; ri++){
            v2f w2 = wf[gte][ri].h[dk >> 1];
            if ((dk & 1) == 0){
              PKFMA_LO(acc[gte][ri].h[0], hv.h[0], w2);
              PKFMA_LO(acc[gte][ri].h[1], hv.h[1], w2);
            } else {
              PKFMA_HI(acc[gte][ri].h[0], hv.h[0], w2);
              PKFMA_HI(acc[gte][ri].h[1], hv.h[1], w2);
            }
          }
      }
    }
  };
  auto ZERO = [&](f4u (&acc)[3][4]){
    #pragma unroll
    for (int a1 = 0; a1 < 3; a1++)
      #pragma unroll
      for (int a2 = 0; a2 < 4; a2++){ float4 z = {0,0,0,0}; acc[a1][a2].f = z; }
  };
  auto REDEX = [&](f4u (&acc)[3][4], float* g3){
    #pragma unroll
    for (int gte = 0; gte < 3; gte++)
      #pragma unroll
      for (int ri = 0; ri < 4; ri++)
        acc[gte][ri].f = kred16(acc[gte][ri].f);
    const int r = kg >> 2, c = kg & 3;
    #pragma unroll
    for (int gte = 0; gte < 3; gte++){
      float4 f0 = (r & 2) ? acc[gte][2].f : acc[gte][0].f;
      float4 f1 = (r & 2) ? acc[gte][3].f : acc[gte][1].f;
      float4 f  = (r & 1) ? f1 : f0;
      float e0 = (c & 2) ? f.z : f.x;
      float e1 = (c & 2) ? f.w : f.y;
      g3[gte] = fold32((c & 1) ? e1 : e0);     // fold the jh halves (lane^32)
    }
  };

  auto WAIT = [&](unsigned* c, unsigned tgt){
    while (__hip_atomic_fetch_add(c, 0u, __ATOMIC_RELAXED, __HIP_MEMORY_SCOPE_AGENT) < tgt)
      __builtin_amdgcn_s_sleep(4);
  };
  auto ARRIVE = [&](unsigned* c){
    __hip_atomic_fetch_add(c, 1u, __ATOMIC_RELAXED, __HIP_MEMORY_SCOPE_AGENT);
  };

  __syncthreads();
  SLOADC(h1b1);                        // h1[-1] = 0
  VMWAIT0();
  SWRITE(HA4);
  __syncthreads();

  for (int t = 0; t < T_TOT; t++){
    const float* h2prev = (t & 1) ? h2b0 : h2b1;
    float* h1nxt = (t & 1) ? h1b1 : h1b0;
    float* h2nxt = (t & 1) ? h2b1 : h2b0;

    if (tid == 0) WAIT(cntB, 32u*(unsigned)t);
    __syncthreads();                                          // bar1
    SLOADC(h2prev);                    // in flight under GEMM0

    // ---------------- layer 0: whh0 . h1[t-1] (HA resident) ----------------
    f4u acc0[3][4]; ZERO(acc0);
    GEMM3(HA4, 0, acc0);
    float g0[3];
    REDEX(acc0, g0);
    float xr = bi0g[0], xz = bi0g[1], xn = bi0g[2];
    if (t < T_IN){
      const float* xp = x + (btb + col)*(T_IN*10) + t*10;
      #pragma unroll
      for (int d = 0; d < 10; d++){
        float xvv = xp[d];
        xr = fmaf(wi0[0][d], xvv, xr);
        xz = fmaf(wi0[1][d], xvv, xz);
        xn = fmaf(wi0[2][d], xvv, xn);
      }
    }
    float r = sigf(xr + g0[0] + bh0g[0]);
    float z = sigf(xz + g0[1] + bh0g[1]);
    float n = tanhfast(xn + r*(g0[2] + bh0g[2]));
    float hnew1 = fmaf(z, HAf[hIdx] - n, n);
    if (!jh) HSTORE(h1nxt + (rowg << 8) + btb + col, hnew1);
    VMWAIT0();                         // h2prev tile arrived + h1 store acked
    SWRITE(HB4);
    __syncthreads();                                          // bar2
    if (tid == 0) ARRIVE(cntA);

    // ---------------- layer 1 part A: whh1 . h2[t-1] ----------------
    f4u acc2[3][4]; ZERO(acc2);
    GEMM3(HB4, 2, acc2);
    float g2[3];
    REDEX(acc2, g2);
    if (tid == 0) WAIT(cntA, 32u*(unsigned)(t + 1));
    __syncthreads();                                          // bar3
    SLOADC(h1nxt);
    VMWAIT0();                         // h1[t] tile arrived
    SWRITE(HA4);                       // feeds GEMM1 now, GEMM0 next step
    __syncthreads();                                          // bar4

    // ---------------- layer 1 part B: wih1 . h1[t] ----------------
    f4u acc1[3][4]; ZERO(acc1);
    GEMM3(HA4, 1, acc1);
    float g1[3];
    REDEX(acc1, g1);
    float r1 = sigf(g1[0] + bi1g[0] + g2[0] + bh1g[0]);
    float z1 = sigf(g1[1] + bi1g[1] + g2[1] + bh1g[1]);
    float n1 = tanhfast(g1[2] + bi1g[2] + r1*(g2[2] + bh1g[2]));
    float h2new = fmaf(z1, HBf[hIdx] - n1, n1);
    if (!jh){
      HSTORE(h2nxt + (rowg << 8) + btb + col, h2new);
      if (t >= T_IN) PRJ[(hrow << 5) + col] = h2new * wp;
    }
    VMWAIT0();                         // h2 store acked
    __syncthreads();                                          // bar5
    if (tid == 0) ARRIVE(cntB);

    if (t >= T_IN && tid < 32){
      float s = 0.0f;
      #pragma unroll
      for (int hh = 0; hh < 8; hh++) s += PRJ[hh*32 + tid];
      atomicAdd(out + (btb + tid)*T_OUT + (t - T_IN), s);
    }
  }
}

extern "C" void kernel_launch(void* const* d_in, const int* in_sizes, int n_in,
                              void* d_out, int out_size, void* d_ws, size_t ws_size,
                              hipStream_t stream){
  const float* x     = (const float*)d_in[0];
  const float* wih0  = (const float*)d_in[1];
  const float* whh0  = (const float*)d_in[2];
  const float* bih0  = (const float*)d_in[3];
  const float* bhh0  = (const float*)d_in[4];
  const float* wih1  = (const float*)d_in[5];
  const float* whh1  = (const float*)d_in[6];
  const float* bih1  = (const float*)d_in[7];
  const float* bhh1  = (const float*)d_in[8];
  const float* wproj = (const float*)d_in[9];
  const float* bproj = (const float*)d_in[10];
  float* out = (float*)d_out;
  float* ws  = (float*)d_ws;

  hipLaunchKernelGGL(gru_init, dim3(1024), dim3(256), 0, stream, ws, out, bproj);

  hipFuncSetAttribute(reinterpret_cast<const void*>(gru_persist),
                      hipFuncAttributeMaxDynamicSharedMemorySize, LDS_BYTES);

  void* args[] = {
    (void*)&x, (void*)&wih0, (void*)&whh0, (void*)&bih0, (void*)&bhh0,
    (void*)&wih1, (void*)&whh1, (void*)&bih1, (void*)&bhh1,
    (void*)&wproj, (void*)&out, (void*)&ws
  };
  hipLaunchCooperativeKernel(reinterpret_cast<void*>(gru_persist),
                             dim3(256), dim3(THREADS), args, LDS_BYTES, stream);
}

// Round 15
// 3802.266 us; speedup vs baseline: 1.0183x; 1.0183x over previous
//
#include <hip/hip_runtime.h>

#define THREADS 256
#define T_TOT 432
#define T_IN  144
#define T_OUT 288

// LDS float4-granule offsets (R13 layout, unchanged)
#define WS4     1552            // per-mat W stride (f4)
#define HA_OFF  4656            // 3*1552
#define HB_OFF  6704            // HA_OFF + 2048
#define PRJ_OFFf 35008          // (HB_OFF+2048)*4 (float index)
#define LDS_BYTES 141056        // (PRJ_OFFf+256)*4

// ws layout (floats): h1b0 [0,64K) h1b1 [64K,128K) h2b0 [128K,192K) h2b1 [192K,256K)
//   (global h layout: [k=256][b=256]) — exchanged via sc0/sc1 (MALL-coherent) ops only
// counters: 512 uints at ws+262144; group bt: cntA = +bt*64, cntB = +bt*64+32
// R15 = R13 (passing, 3.79ms) + ONE change: WAIT polls via sc01 LOAD (reads don't
// serialize at the MALL like RMWs; 31 pollers were saturating the counter line's
// RMW queue and delaying producers' ARRIVEs). ARRIVE stays a relaxed RMW.

typedef float v2f __attribute__((ext_vector_type(2)));
union f4u { float4 f; v2f h[2]; };

#define PKFMA_LO(acc, hh, w2) asm("v_pk_fma_f32 %0, %1, %2, %0 op_sel:[0,0,0] op_sel_hi:[1,0,1]" \
                                  : "+v"(acc) : "v"(hh), "v"(w2))
#define PKFMA_HI(acc, hh, w2) asm("v_pk_fma_f32 %0, %1, %2, %0 op_sel:[0,1,0] op_sel_hi:[1,1,1]" \
                                  : "+v"(acc) : "v"(hh), "v"(w2))

#define VMWAIT0() do { asm volatile("s_waitcnt vmcnt(0)" ::: "memory"); \
                       __builtin_amdgcn_sched_barrier(0); } while(0)

__device__ __forceinline__ float sigf(float x){ return 1.0f/(1.0f + __expf(-x)); }
__device__ __forceinline__ float tanhfast(float x){ return 1.0f - 2.0f/(__expf(2.0f*x)+1.0f); }

template<int CTRL>
__device__ __forceinline__ float4 dpp_add(float4 v){
  float4 r;
  r.x = v.x + __int_as_float(__builtin_amdgcn_update_dpp(0, __float_as_int(v.x), CTRL, 0xf, 0xf, true));
  r.y = v.y + __int_as_float(__builtin_amdgcn_update_dpp(0, __float_as_int(v.y), CTRL, 0xf, 0xf, true));
  r.z = v.z + __int_as_float(__builtin_amdgcn_update_dpp(0, __float_as_int(v.z), CTRL, 0xf, 0xf, true));
  r.w = v.w + __int_as_float(__builtin_amdgcn_update_dpp(0, __float_as_int(v.w), CTRL, 0xf, 0xf, true));
  return r;
}
// full 16-lane K-reduction (proven R9/R13)
__device__ __forceinline__ float4 kred16(float4 v){
  v = dpp_add<177>(v);     // quad_perm [1,0,3,2]
  v = dpp_add<78>(v);      // quad_perm [2,3,0,1]
  v = dpp_add<0x141>(v);   // ROW_HALF_MIRROR
  v = dpp_add<0x140>(v);   // ROW_MIRROR
  return v;
}

extern "C" __global__ void gru_init(float* __restrict__ ws, float* __restrict__ out,
                                    const float* __restrict__ b_proj){
  int i = blockIdx.x*THREADS + threadIdx.x;
  if (i < 262144) ws[i] = 0.0f;
  if (i < 512) ((unsigned*)(ws + 262144))[i] = 0u;
  if (i < 73728) out[i] = b_proj[0];
}

typedef float v4f __attribute__((ext_vector_type(4)));

extern "C" __global__ void __launch_bounds__(THREADS, 1) gru_persist(
    const float* __restrict__ x,
    const float* __restrict__ wih0, const float* __restrict__ whh0,
    const float* __restrict__ bih0, const float* __restrict__ bhh0,
    const float* __restrict__ wih1, const float* __restrict__ whh1,
    const float* __restrict__ bih1, const float* __restrict__ bhh1,
    const float* __restrict__ wproj,
    float* __restrict__ out, float* __restrict__ ws)
{
  extern __shared__ float lds[];
  float4* WL4 = (float4*)lds;
  float4* HA4 = WL4 + HA_OFF;
  float4* HB4 = WL4 + HB_OFF;
  const float* HAf = (const float*)HA4;
  const float* HBf = (const float*)HB4;
  float* PRJ = lds + PRJ_OFFf;

  const int tid = threadIdx.x;
  const int bt  = blockIdx.x & 7;     // batch tile (XCD-local group)
  const int g   = blockIdx.x >> 3;    // hidden slice (8 rows)
  const int kg   = tid & 15;          // 16-way K split (in-wave)
  const int wv   = tid >> 6;
  const int rh   = wv >> 1;           // row half
  const int cq   = ((wv & 1) << 2) | ((tid >> 4) & 3);   // col quad 0..7
  // owner cell (lane-local extraction, proven R9)
  const int hrow = (rh << 2) | (kg >> 2);
  const int col  = (cq << 2) | (kg & 3);
  const int rowg = g*8 + hrow;
  const int btb  = bt << 5;

  float* h1b0 = ws;
  float* h1b1 = ws + 65536;
  float* h2b0 = ws + 131072;
  float* h2b1 = ws + 196608;
  unsigned* cntA = ((unsigned*)(ws + 262144)) + (bt << 6);
  unsigned* cntB = cntA + 32;

  // ---- one-time: W slices -> LDS [k4*24 + row + (k4>>2)] ----
  {
    const float* srcs[3] = {whh0, wih1, whh1};
    #pragma unroll
    for (int m = 0; m < 3; m++){
      const float* S = srcs[m];
      for (int i = 0; i < 6; i++){
        int idx = tid + (i << 8);
        int row = idx % 24;
        int k4  = idx / 24;
        int gate = row >> 3, hh = row & 7;
        float4 v = *(const float4*)(S + (gate*256 + g*8 + hh)*256 + (k4 << 2));
        WL4[m*WS4 + k4*24 + row + (k4 >> 2)] = v;
      }
    }
  }
  float wi0[3][10];
  float bi0g[3], bh0g[3], bi1g[3], bh1g[3];
  #pragma unroll
  for (int G = 0; G < 3; G++){
    #pragma unroll
    for (int d = 0; d < 10; d++) wi0[G][d] = wih0[(G*256 + rowg)*10 + d];
    bi0g[G] = bih0[G*256 + rowg];
    bh0g[G] = bhh0[G*256 + rowg];
    bi1g[G] = bih1[G*256 + rowg];
    bh1g[G] = bhh1[G*256 + rowg];
  }
  const float wp = wproj[rowg];
  const int hIdx = (rowg << 5) + ((((col >> 2) + (rowg >> 4)) & 7) << 2) + (col & 3);

  v4f hreg[8];
  auto SLOADC = [&](const float* __restrict__ hg){
    #pragma unroll
    for (int i = 0; i < 8; i++){
      int idx = tid + (i << 8);
      const float* p = hg + ((idx >> 3) << 8) + btb + ((idx & 7) << 2);
      asm volatile("global_load_dwordx4 %0, %1, off sc0 sc1"
                   : "=v"(hreg[i]) : "v"(p) : "memory");
    }
  };
  auto SWRITE = [&](float4* __restrict__ H4){
    #pragma unroll
    for (int i = 0; i < 8; i++){
      int idx = tid + (i << 8);
      int k = idx >> 3, q = idx & 7;
      *(v4f*)&H4[(k << 3) + ((q + (k >> 4)) & 7)] = hreg[i];
    }
  };
  auto HSTORE = [&](float* p, float v){
    asm volatile("global_store_dword %0, %1, off sc0 sc1" :: "v"(p), "v"(v) : "memory");
  };

  // ---- GEMM: 12 rows x 1 quad x 16 k; R13 addressing, packed v_pk_fma_f32 ----
  auto GEMM3 = [&](const float4* __restrict__ H4, int m, f4u (&acc)[3][4]){
    const int wb = m*WS4;
    #pragma unroll
    for (int j = 0; j < 4; j++){
      const int k4 = (kg << 2) + j;
      const int wr = wb + k4*24 + (k4 >> 2);   // skew k4>>2 == kg
      f4u wf[3][4];
      #pragma unroll
      for (int gte = 0; gte < 3; gte++)
        #pragma unroll
        for (int ri = 0; ri < 4; ri++)
          wf[gte][ri].f = WL4[wr + (gte << 3) + (rh << 2) + ri];
      #pragma unroll
      for (int dk = 0; dk < 4; dk++){
        const int kidx = (k4 << 2) + dk;
        f4u hv; hv.f = H4[(kidx << 3) + ((cq + kg) & 7)];
        #pragma unroll
        for (int gte = 0; gte < 3; gte++)
          #pragma unroll
          for (int ri = 0; ri < 4; ri++){
            v2f w2 = wf[gte][ri].h[dk >> 1];
            if ((dk & 1) == 0){
              PKFMA_LO(acc[gte][ri].h[0], hv.h[0], w2);
              PKFMA_LO(acc[gte][ri].h[1], hv.h[1], w2);
            } else {
              PKFMA_HI(acc[gte][ri].h[0], hv.h[0], w2);
              PKFMA_HI(acc[gte][ri].h[1], hv.h[1], w2);
            }
          }
      }
    }
  };
  auto ZERO = [&](f4u (&acc)[3][4]){
    #pragma unroll
    for (int a1 = 0; a1 < 3; a1++)
      #pragma unroll
      for (int a2 = 0; a2 < 4; a2++){ float4 z = {0,0,0,0}; acc[a1][a2].f = z; }
  };
  auto REDEX = [&](f4u (&acc)[3][4], float* g3){
    #pragma unroll
    for (int gte = 0; gte < 3; gte++)
      #pragma unroll
      for (int ri = 0; ri < 4; ri++)
        acc[gte][ri].f = kred16(acc[gte][ri].f);
    const int r = kg >> 2, c = kg & 3;
    #pragma unroll
    for (int gte = 0; gte < 3; gte++){
      float4 f0 = (r & 2) ? acc[gte][2].f : acc[gte][0].f;
      float4 f1 = (r & 2) ? acc[gte][3].f : acc[gte][1].f;
      float4 f  = (r & 1) ? f1 : f0;
      float e0 = (c & 2) ? f.z : f.x;
      float e1 = (c & 2) ? f.w : f.y;
      g3[gte] = (c & 1) ? e1 : e0;
    }
  };

  // poll via MALL-coherent LOAD (no RMW serialization); tid0 only
  auto WAIT = [&](unsigned* c, unsigned tgt){
    for (;;){
      unsigned v;
      asm volatile("global_load_dword %0, %1, off sc0 sc1\n\t"
                   "s_waitcnt vmcnt(0)"
                   : "=v"(v) : "v"(c) : "memory");
      if (v >= tgt) break;
      __builtin_amdgcn_s_sleep(1);
    }
  };
  auto ARRIVE = [&](unsigned* c){
    __hip_atomic_fetch_add(c, 1u, __ATOMIC_RELAXED, __HIP_MEMORY_SCOPE_AGENT);
  };

  __syncthreads();
  SLOADC(h1b1);                        // h1[-1] = 0
  VMWAIT0();
  SWRITE(HA4);
  __syncthreads();

  for (int t = 0; t < T_TOT; t++){
    const float* h2prev = (t & 1) ? h2b0 : h2b1;
    float* h1nxt = (t & 1) ? h1b1 : h1b0;
    float* h2nxt = (t & 1) ? h2b1 : h2b0;

    if (tid == 0) WAIT(cntB, 32u*(unsigned)t);
    __syncthreads();                                          // bar1
    SLOADC(h2prev);                    // in flight under GEMM0

    // ---------------- layer 0: whh0 . h1[t-1] (HA resident) ----------------
    f4u acc0[3][4]; ZERO(acc0);
    GEMM3(HA4, 0, acc0);
    float g0[3];
    REDEX(acc0, g0);
    float xr = bi0g[0], xz = bi0g[1], xn = bi0g[2];
    if (t < T_IN){
      const float* xp = x + (btb + col)*(T_IN*10) + t*10;
      #pragma unroll
      for (int d = 0; d < 10; d++){
        float xvv = xp[d];
        xr = fmaf(wi0[0][d], xvv, xr);
        xz = fmaf(wi0[1][d], xvv, xz);
        xn = fmaf(wi0[2][d], xvv, xn);
      }
    }
    float r = sigf(xr + g0[0] + bh0g[0]);
    float z = sigf(xz + g0[1] + bh0g[1]);
    float n = tanhfast(xn + r*(g0[2] + bh0g[2]));
    float hnew1 = fmaf(z, HAf[hIdx] - n, n);
    HSTORE(h1nxt + (rowg << 8) + btb + col, hnew1);
    VMWAIT0();                         // h2prev tile arrived + h1 store acked
    SWRITE(HB4);
    __syncthreads();                                          // bar2
    if (tid == 0) ARRIVE(cntA);

    // ---------------- layer 1 part A: whh1 . h2[t-1] ----------------
    f4u acc2[3][4]; ZERO(acc2);
    GEMM3(HB4, 2, acc2);
    float g2[3];
    REDEX(acc2, g2);
    if (tid == 0) WAIT(cntA, 32u*(unsigned)(t + 1));
    __syncthreads();                                          // bar3
    SLOADC(h1nxt);
    VMWAIT0();                         // h1[t] tile arrived
    SWRITE(HA4);                       // feeds GEMM1 now, GEMM0 next step
    __syncthreads();                                          // bar4

    // ---------------- layer 1 part B: wih1 . h1[t] ----------------
    f4u acc1[3][4]; ZERO(acc1);
    GEMM3(HA4, 1, acc1);
    float g1[3];
    REDEX(acc1, g1);
    float r1 = sigf(g1[0] + bi1g[0] + g2[0] + bh1g[0]);
    float z1 = sigf(g1[1] + bi1g[1] + g2[1] + bh1g[1]);
    float n1 = tanhfast(g1[2] + bi1g[2] + r1*(g2[2] + bh1g[2]));
    float h2new = fmaf(z1, HBf[hIdx] - n1, n1);
    HSTORE(h2nxt + (rowg << 8) + btb + col, h2new);
    if (t >= T_IN) PRJ[(hrow << 5) + col] = h2new * wp;
    VMWAIT0();                         // h2 store acked
    __syncthreads();                                          // bar5
    if (tid == 0) ARRIVE(cntB);

    if (t >= T_IN && tid < 32){
      float s = 0.0f;
      #pragma unroll
      for (int hh = 0; hh < 8; hh++) s += PRJ[hh*32 + tid];
      atomicAdd(out + (btb + tid)*T_OUT + (t - T_IN), s);
    }
  }
}

extern "C" void kernel_launch(void* const* d_in, const int* in_sizes, int n_in,
                              void* d_out, int out_size, void* d_ws, size_t ws_size,
                              hipStream_t stream){
  const float* x     = (const float*)d_in[0];
  const float* wih0  = (const float*)d_in[1];
  const float* whh0  = (const float*)d_in[2];
  const float* bih0  = (const float*)d_in[3];
  const float* bhh0  = (const float*)d_in[4];
  const float* wih1  = (const float*)d_in[5];
  const float* whh1  = (const float*)d_in[6];
  const float* bih1  = (const float*)d_in[7];
  const float* bhh1  = (const float*)d_in[8];
  const float* wproj = (const float*)d_in[9];
  const float* bproj = (const float*)d_in[10];
  float* out = (float*)d_out;
  float* ws  = (float*)d_ws;

  hipLaunchKernelGGL(gru_init, dim3(1024), dim3(THREADS), 0, stream, ws, out, bproj);

  hipFuncSetAttribute(reinterpret_cast<const void*>(gru_persist),
                      hipFuncAttributeMaxDynamicSharedMemorySize, LDS_BYTES);

  void* args[] = {
    (void*)&x, (void*)&wih0, (void*)&whh0, (void*)&bih0, (void*)&bhh0,
    (void*)&wih1, (void*)&whh1, (void*)&bih1, (void*)&bhh1,
    (void*)&wproj, (void*)&out, (void*)&ws
  };
  hipLaunchCooperativeKernel(reinterpret_cast<void*>(gru_persist),
                             dim3(256), dim3(THREADS), args, LDS_BYTES, stream);
}

// Round 19
// 3739.911 us; speedup vs baseline: 1.0353x; 1.0167x over previous
//
#include <hip/hip_runtime.h>

#define THREADS 256
#define T_TOT 432
#define T_IN  144
#define T_OUT 288

// LDS float4-granule offsets (R13 layout, unchanged)
#define WS4     1552            // per-mat W stride (f4)
#define HA_OFF  4656            // 3*1552
#define HB_OFF  6704            // HA_OFF + 2048
#define PRJ_OFFf 35008          // (HB_OFF+2048)*4 (float index)
#define LDS_BYTES 141056        // (PRJ_OFFf+256)*4

// ws layout (floats): h1b0 [0,64K) h1b1 [64K,128K) h2b0 [128K,192K) h2b1 [192K,256K)
//   (global h layout: [k=256][b=256]) — exchanged via sc0/sc1 (MALL-coherent) ops only
// counters: 512 uints at ws+262144; group bt: cntA = +bt*64, cntB = +bt*64+32
// R19 = R13 BODY BYTE-IDENTICAL (proven 3.79ms, VGPR 128) + PLAIN LAUNCH.
// R18 proved hipLaunchCooperativeKernel was silently rejecting larger kernels
// (unchecked return) — the seven "bit-identical 5.023e-2" rounds never ran.
// Plain launch executes (R18 ran and NaN'd — that body exceeded the 256-arch-VGPR
// wall, displacing inline-asm load outputs to AGPRs before vmcnt). R13's body is
// 128 VGPR — no displacement hazard. Flag barriers need only co-residency:
// 256 blocks @ 1 block/CU (LDS-bound) on 256 CUs.

typedef float v2f __attribute__((ext_vector_type(2)));
union f4u { float4 f; v2f h[2]; };

// packed fp32 fma: acc(2) += h(2) * broadcast(w-component)
#define PKFMA_LO(acc, hh, w2) asm("v_pk_fma_f32 %0, %1, %2, %0 op_sel:[0,0,0] op_sel_hi:[1,0,1]" \
                                  : "+v"(acc) : "v"(hh), "v"(w2))
#define PKFMA_HI(acc, hh, w2) asm("v_pk_fma_f32 %0, %1, %2, %0 op_sel:[0,1,0] op_sel_hi:[1,1,1]" \
                                  : "+v"(acc) : "v"(hh), "v"(w2))

#define VMWAIT0() do { asm volatile("s_waitcnt vmcnt(0)" ::: "memory"); \
                       __builtin_amdgcn_sched_barrier(0); } while(0)

__device__ __forceinline__ float sigf(float x){ return 1.0f/(1.0f + __expf(-x)); }
__device__ __forceinline__ float tanhfast(float x){ return 1.0f - 2.0f/(__expf(2.0f*x)+1.0f); }

template<int CTRL>
__device__ __forceinline__ float4 dpp_add(float4 v){
  float4 r;
  r.x = v.x + __int_as_float(__builtin_amdgcn_update_dpp(0, __float_as_int(v.x), CTRL, 0xf, 0xf, true));
  r.y = v.y + __int_as_float(__builtin_amdgcn_update_dpp(0, __float_as_int(v.y), CTRL, 0xf, 0xf, true));
  r.z = v.z + __int_as_float(__builtin_amdgcn_update_dpp(0, __float_as_int(v.z), CTRL, 0xf, 0xf, true));
  r.w = v.w + __int_as_float(__builtin_amdgcn_update_dpp(0, __float_as_int(v.w), CTRL, 0xf, 0xf, true));
  return r;
}
// full 16-lane K-reduction (proven R9/R13)
__device__ __forceinline__ float4 kred16(float4 v){
  v = dpp_add<177>(v);     // quad_perm [1,0,3,2]
  v = dpp_add<78>(v);      // quad_perm [2,3,0,1]
  v = dpp_add<0x141>(v);   // ROW_HALF_MIRROR (xor4; valid, bits0-1 uniform)
  v = dpp_add<0x140>(v);   // ROW_MIRROR (xor8)
  return v;
}

extern "C" __global__ void gru_init(float* __restrict__ ws, float* __restrict__ out,
                                    const float* __restrict__ b_proj){
  int i = blockIdx.x*THREADS + threadIdx.x;
  if (i < 262144) ws[i] = 0.0f;
  if (i < 512) ((unsigned*)(ws + 262144))[i] = 0u;
  if (i < 73728) out[i] = b_proj[0];
}

typedef float v4f __attribute__((ext_vector_type(4)));

extern "C" __global__ void __launch_bounds__(THREADS, 1) gru_persist(
    const float* __restrict__ x,
    const float* __restrict__ wih0, const float* __restrict__ whh0,
    const float* __restrict__ bih0, const float* __restrict__ bhh0,
    const float* __restrict__ wih1, const float* __restrict__ whh1,
    const float* __restrict__ bih1, const float* __restrict__ bhh1,
    const float* __restrict__ wproj,
    float* __restrict__ out, float* __restrict__ ws)
{
  extern __shared__ float lds[];
  float4* WL4 = (float4*)lds;
  float4* HA4 = WL4 + HA_OFF;
  float4* HB4 = WL4 + HB_OFF;
  const float* HAf = (const float*)HA4;
  const float* HBf = (const float*)HB4;
  float* PRJ = lds + PRJ_OFFf;

  const int tid = threadIdx.x;
  const int bt  = blockIdx.x & 7;     // batch tile (XCD-local group)
  const int g   = blockIdx.x >> 3;    // hidden slice (8 rows)
  const int kg   = tid & 15;          // 16-way K split (in-wave)
  const int wv   = tid >> 6;
  const int rh   = wv >> 1;           // row half
  const int cq   = ((wv & 1) << 2) | ((tid >> 4) & 3);   // col quad 0..7
  // owner cell (lane-local extraction, proven R9)
  const int hrow = (rh << 2) | (kg >> 2);
  const int col  = (cq << 2) | (kg & 3);
  const int rowg = g*8 + hrow;
  const int btb  = bt << 5;

  float* h1b0 = ws;
  float* h1b1 = ws + 65536;
  float* h2b0 = ws + 131072;
  float* h2b1 = ws + 196608;
  unsigned* cntA = ((unsigned*)(ws + 262144)) + (bt << 6);
  unsigned* cntB = cntA + 32;

  // ---- one-time: W slices -> LDS [k4*24 + row + (k4>>2)] ----
  {
    const float* srcs[3] = {whh0, wih1, whh1};
    #pragma unroll
    for (int m = 0; m < 3; m++){
      const float* S = srcs[m];
      for (int i = 0; i < 6; i++){
        int idx = tid + (i << 8);
        int row = idx % 24;
        int k4  = idx / 24;
        int gate = row >> 3, hh = row & 7;
        float4 v = *(const float4*)(S + (gate*256 + g*8 + hh)*256 + (k4 << 2));
        WL4[m*WS4 + k4*24 + row + (k4 >> 2)] = v;
      }
    }
  }
  float wi0[3][10];
  float bi0g[3], bh0g[3], bi1g[3], bh1g[3];
  #pragma unroll
  for (int G = 0; G < 3; G++){
    #pragma unroll
    for (int d = 0; d < 10; d++) wi0[G][d] = wih0[(G*256 + rowg)*10 + d];
    bi0g[G] = bih0[G*256 + rowg];
    bh0g[G] = bhh0[G*256 + rowg];
    bi1g[G] = bih1[G*256 + rowg];
    bh1g[G] = bhh1[G*256 + rowg];
  }
  const float wp = wproj[rowg];
  const int hIdx = (rowg << 5) + ((((col >> 2) + (rowg >> 4)) & 7) << 2) + (col & 3);

  v4f hreg[8];
  auto SLOADC = [&](const float* __restrict__ hg){
    #pragma unroll
    for (int i = 0; i < 8; i++){
      int idx = tid + (i << 8);
      const float* p = hg + ((idx >> 3) << 8) + btb + ((idx & 7) << 2);
      asm volatile("global_load_dwordx4 %0, %1, off sc0 sc1"
                   : "=v"(hreg[i]) : "v"(p) : "memory");
    }
  };
  auto SWRITE = [&](float4* __restrict__ H4){
    #pragma unroll
    for (int i = 0; i < 8; i++){
      int idx = tid + (i << 8);
      int k = idx >> 3, q = idx & 7;
      *(v4f*)&H4[(k << 3) + ((q + (k >> 4)) & 7)] = hreg[i];
    }
  };
  auto HSTORE = [&](float* p, float v){
    asm volatile("global_store_dword %0, %1, off sc0 sc1" :: "v"(p), "v"(v) : "memory");
  };

  // ---- GEMM: 12 rows x 1 quad x 16 k; R13 addressing, packed v_pk_fma_f32 ----
  auto GEMM3 = [&](const float4* __restrict__ H4, int m, f4u (&acc)[3][4]){
    const int wb = m*WS4;
    #pragma unroll
    for (int j = 0; j < 4; j++){
      const int k4 = (kg << 2) + j;
      const int wr = wb + k4*24 + (k4 >> 2);   // skew k4>>2 == kg
      f4u wf[3][4];
      #pragma unroll
      for (int gte = 0; gte < 3; gte++)
        #pragma unroll
        for (int ri = 0; ri < 4; ri++)
          wf[gte][ri].f = WL4[wr + (gte << 3) + (rh << 2) + ri];
      #pragma unroll
      for (int dk = 0; dk < 4; dk++){
        const int kidx = (k4 << 2) + dk;
        f4u hv; hv.f = H4[(kidx << 3) + ((cq + kg) & 7)];
        #pragma unroll
        for (int gte = 0; gte < 3; gte++)
          #pragma unroll
          for (int ri = 0; ri < 4; ri++){
            v2f w2 = wf[gte][ri].h[dk >> 1];   // (x,y) for dk 0/1, (z,w) for dk 2/3
            if ((dk & 1) == 0){
              PKFMA_LO(acc[gte][ri].h[0], hv.h[0], w2);
              PKFMA_LO(acc[gte][ri].h[1], hv.h[1], w2);
            } else {
              PKFMA_HI(acc[gte][ri].h[0], hv.h[0], w2);
              PKFMA_HI(acc[gte][ri].h[1], hv.h[1], w2);
            }
          }
      }
    }
  };
  auto ZERO = [&](f4u (&acc)[3][4]){
    #pragma unroll
    for (int a1 = 0; a1 < 3; a1++)
      #pragma unroll
      for (int a2 = 0; a2 < 4; a2++){ float4 z = {0,0,0,0}; acc[a1][a2].f = z; }
  };
  auto REDEX = [&](f4u (&acc)[3][4], float* g3){
    #pragma unroll
    for (int gte = 0; gte < 3; gte++)
      #pragma unroll
      for (int ri = 0; ri < 4; ri++)
        acc[gte][ri].f = kred16(acc[gte][ri].f);
    const int r = kg >> 2, c = kg & 3;
    #pragma unroll
    for (int gte = 0; gte < 3; gte++){
      float4 f0 = (r & 2) ? acc[gte][2].f : acc[gte][0].f;
      float4 f1 = (r & 2) ? acc[gte][3].f : acc[gte][1].f;
      float4 f  = (r & 1) ? f1 : f0;
      float e0 = (c & 2) ? f.z : f.x;
      float e1 = (c & 2) ? f.w : f.y;
      g3[gte] = (c & 1) ? e1 : e0;
    }
  };

  auto WAIT = [&](unsigned* c, unsigned tgt){
    while (__hip_atomic_fetch_add(c, 0u, __ATOMIC_RELAXED, __HIP_MEMORY_SCOPE_AGENT) < tgt)
      __builtin_amdgcn_s_sleep(4);
  };
  auto ARRIVE = [&](unsigned* c){
    __hip_atomic_fetch_add(c, 1u, __ATOMIC_RELAXED, __HIP_MEMORY_SCOPE_AGENT);
  };

  __syncthreads();
  SLOADC(h1b1);                        // h1[-1] = 0
  VMWAIT0();
  SWRITE(HA4);
  __syncthreads();

  for (int t = 0; t < T_TOT; t++){
    const float* h2prev = (t & 1) ? h2b0 : h2b1;
    float* h1nxt = (t & 1) ? h1b1 : h1b0;
    float* h2nxt = (t & 1) ? h2b1 : h2b0;

    if (tid == 0) WAIT(cntB, 32u*(unsigned)t);
    __syncthreads();                                          // bar1
    SLOADC(h2prev);                    // in flight under GEMM0

    // ---------------- layer 0: whh0 . h1[t-1] (HA resident) ----------------
    f4u acc0[3][4]; ZERO(acc0);
    GEMM3(HA4, 0, acc0);
    float g0[3];
    REDEX(acc0, g0);
    float xr = bi0g[0], xz = bi0g[1], xn = bi0g[2];
    if (t < T_IN){
      const float* xp = x + (btb + col)*(T_IN*10) + t*10;
      #pragma unroll
      for (int d = 0; d < 10; d++){
        float xvv = xp[d];
        xr = fmaf(wi0[0][d], xvv, xr);
        xz = fmaf(wi0[1][d], xvv, xz);
        xn = fmaf(wi0[2][d], xvv, xn);
      }
    }
    float r = sigf(xr + g0[0] + bh0g[0]);
    float z = sigf(xz + g0[1] + bh0g[1]);
    float n = tanhfast(xn + r*(g0[2] + bh0g[2]));
    float hnew1 = fmaf(z, HAf[hIdx] - n, n);
    HSTORE(h1nxt + (rowg << 8) + btb + col, hnew1);
    VMWAIT0();                         // h2prev tile arrived + h1 store acked
    SWRITE(HB4);
    __syncthreads();                                          // bar2
    if (tid == 0) ARRIVE(cntA);

    // ---------------- layer 1 part A: whh1 . h2[t-1] ----------------
    f4u acc2[3][4]; ZERO(acc2);
    GEMM3(HB4, 2, acc2);
    float g2[3];
    REDEX(acc2, g2);
    if (tid == 0) WAIT(cntA, 32u*(unsigned)(t + 1));
    __syncthreads();                                          // bar3
    SLOADC(h1nxt);
    VMWAIT0();                         // h1[t] tile arrived
    SWRITE(HA4);                       // feeds GEMM1 now, GEMM0 next step
    __syncthreads();                                          // bar4

    // ---------------- layer 1 part B: wih1 . h1[t] ----------------
    f4u acc1[3][4]; ZERO(acc1);
    GEMM3(HA4, 1, acc1);
    float g1[3];
    REDEX(acc1, g1);
    float r1 = sigf(g1[0] + bi1g[0] + g2[0] + bh1g[0]);
    float z1 = sigf(g1[1] + bi1g[1] + g2[1] + bh1g[1]);
    float n1 = tanhfast(g1[2] + bi1g[2] + r1*(g2[2] + bh1g[2]));
    float h2new = fmaf(z1, HBf[hIdx] - n1, n1);
    HSTORE(h2nxt + (rowg << 8) + btb + col, h2new);
    if (t >= T_IN) PRJ[(hrow << 5) + col] = h2new * wp;
    VMWAIT0();                         // h2 store acked
    __syncthreads();                                          // bar5
    if (tid == 0) ARRIVE(cntB);

    if (t >= T_IN && tid < 32){
      float s = 0.0f;
      #pragma unroll
      for (int hh = 0; hh < 8; hh++) s += PRJ[hh*32 + tid];
      atomicAdd(out + (btb + tid)*T_OUT + (t - T_IN), s);
    }
  }
}

extern "C" void kernel_launch(void* const* d_in, const int* in_sizes, int n_in,
                              void* d_out, int out_size, void* d_ws, size_t ws_size,
                              hipStream_t stream){
  const float* x     = (const float*)d_in[0];
  const float* wih0  = (const float*)d_in[1];
  const float* whh0  = (const float*)d_in[2];
  const float* bih0  = (const float*)d_in[3];
  const float* bhh0  = (const float*)d_in[4];
  const float* wih1  = (const float*)d_in[5];
  const float* whh1  = (const float*)d_in[6];
  const float* bih1  = (const float*)d_in[7];
  const float* bhh1  = (const float*)d_in[8];
  const float* wproj = (const float*)d_in[9];
  const float* bproj = (const float*)d_in[10];
  float* out = (float*)d_out;
  float* ws  = (float*)d_ws;

  hipLaunchKernelGGL(gru_init, dim3(1024), dim3(THREADS), 0, stream, ws, out, bproj);

  hipFuncSetAttribute(reinterpret_cast<const void*>(gru_persist),
                      hipFuncAttributeMaxDynamicSharedMemorySize, LDS_BYTES);

  // PLAIN launch (R19's single change vs R13): no grid.sync() used anywhere;
  // 256 blocks @ 1 block/CU co-reside on 256 CUs. Cooperative launch was
  // silently rejecting larger kernels (unchecked return) — see R18.
  hipLaunchKernelGGL(gru_persist, dim3(256), dim3(THREADS), LDS_BYTES, stream,
                     x, wih0, whh0, bih0, bhh0, wih1, whh1, bih1, bhh1,
                     wproj, out, ws);
}